// Round 13
// baseline (324.646 us; speedup 1.0000x reference)
//
#include <hip/hip_runtime.h>
#include <hip/hip_bf16.h>
#include <stdint.h>

#define M_DIM 4096
#define N_DIM 11008
#define K_DIM 4096
#define KP    (K_DIM / 2)   // packed int32s per weight row

typedef __attribute__((ext_vector_type(4))) int i32x4;

#define AS1 __attribute__((address_space(1)))
#define AS3 __attribute__((address_space(3)))

// ---------------- Fused pre-pass: quant_x (blocks 0..4095) + pack_q (blocks 4096..6143) ----------------
__global__ __launch_bounds__(256) void prep(const float* __restrict__ x,
                                            const int* __restrict__ pw,
                                            signed char* __restrict__ xq,
                                            signed char* __restrict__ wq,
                                            float* __restrict__ r,
                                            float* __restrict__ sx) {
  const int b = blockIdx.x;
  const int t = threadIdx.x;
  if (b < 4096) {
    // --- per-row quantize x -> i8, emit r[b]=sum(x), sx[b]=scale ---
    const int row = b;
    const int lane = t & 63, wid = t >> 6;
    const float4* x4 = (const float4*)(x + (size_t)row * K_DIM);
    float4 v[4];
    float am = 0.0f, sm = 0.0f;
#pragma unroll
    for (int i = 0; i < 4; ++i) {
      v[i] = x4[i * 256 + t];
      sm += v[i].x + v[i].y + v[i].z + v[i].w;
      am = fmaxf(am, fmaxf(fmaxf(fabsf(v[i].x), fabsf(v[i].y)),
                           fmaxf(fabsf(v[i].z), fabsf(v[i].w))));
    }
#pragma unroll
    for (int off = 32; off >= 1; off >>= 1) {
      am = fmaxf(am, __shfl_xor(am, off));
      sm += __shfl_xor(sm, off);
    }
    __shared__ float smax[4], ssum[4];
    if (lane == 0) { smax[wid] = am; ssum[wid] = sm; }
    __syncthreads();
    am = fmaxf(fmaxf(smax[0], smax[1]), fmaxf(smax[2], smax[3]));
    sm = ssum[0] + ssum[1] + ssum[2] + ssum[3];
    const float inv = am > 0.0f ? 127.0f / am : 0.0f;
    unsigned int* xo = (unsigned int*)(xq + (size_t)row * K_DIM);
#pragma unroll
    for (int i = 0; i < 4; ++i) {
      int q0 = min(127, max(-127, __float2int_rn(v[i].x * inv)));
      int q1 = min(127, max(-127, __float2int_rn(v[i].y * inv)));
      int q2 = min(127, max(-127, __float2int_rn(v[i].z * inv)));
      int q3 = min(127, max(-127, __float2int_rn(v[i].w * inv)));
      xo[i * 256 + t] = ((unsigned int)q0 & 0xFF) | (((unsigned int)q1 & 0xFF) << 8) |
                        (((unsigned int)q2 & 0xFF) << 16) | (((unsigned int)q3 & 0xFF) << 24);
    }
    if (t == 0) { r[row] = sm; sx[row] = am > 0.0f ? am / 127.0f : 0.0f; }
  } else {
    // --- repack nibbles -> q' = 2q-15 as i8 [N][K] ---
    const int total = (N_DIM * KP) / 4;  // int4 items; 4 int32 -> 8 i8
    for (int i = (b - 4096) * 256 + t; i < total; i += 2048 * 256) {
      int4 p = ((const int4*)pw)[i];
      int v[4] = {p.x, p.y, p.z, p.w};
      unsigned int u0 = 0, u1 = 0;
#pragma unroll
      for (int j = 0; j < 2; ++j) {
        unsigned int b0 = (unsigned int)(2 * (v[j] & 15) - 15) & 0xFF;
        unsigned int b1 = (unsigned int)(2 * ((v[j] >> 4) & 15) - 15) & 0xFF;
        u0 |= (b0 | (b1 << 8)) << (16 * j);
      }
#pragma unroll
      for (int j = 0; j < 2; ++j) {
        unsigned int b0 = (unsigned int)(2 * (v[2 + j] & 15) - 15) & 0xFF;
        unsigned int b1 = (unsigned int)(2 * ((v[2 + j] >> 4) & 15) - 15) & 0xFF;
        u1 |= (b0 | (b1 << 8)) << (16 * j);
      }
      uint2 st; st.x = u0; st.y = u1;
      ((uint2*)wq)[i] = st;
    }
  }
}

// ---------------- Main: 256x256 tile, BK=128 (i8), A-in-LDS / B-in-registers i8 MFMA GEMM ----------------
// G'[M,N] = Xq[M,K] @ Wq[N,K]^T in i32; epilogue: out = s[o]*(0.5*sx[b]*G' + (7.5-zp[o])*r[b]).
// R13 change: B bypasses LDS. R11/R12 showed the wall is the single LDS pipe serialized
// against MFMA by block-wide barriers (192KB reads + 64KB writes vs 2613 MFMA cyc/K-tile).
// B-fragments are loaded straight from global: lane (lr,lk) reads Wq[row=...+lr][k=..+lk*16]
// -- byte-identical to the LDS fragments of R7-R12 (validated layout), 16 fully-used 64B L2
// lines per instruction, B-panel (2.75MB) L2-resident under the tn-sharing XCD swizzle.
// LDS now holds only A (2 parities x 2 halves x 16KB = 64KB, same 128B-row XOR swizzle,
// 0 conflicts R7-R12): reads 128KB + writes 32KB/K-tile < MFMA time -> pipes can overlap.
// Mid-tile barrier deleted (it only protected B slots): ONE barrier + WAITV(0) per K-tile
// (all loads are ~2600cyc old at the fence -> drain is free). B regs split-prefetched:
// kk1(t) and kk0(t+1) issued at P1, consumed ~1300cyc later; peak B regs 48.
#define BM 256
#define BN 256
#define BK 128                  // i8 elements per K-tile
#define NTILE (K_DIM / BK)      // 32
#define NT_M (M_DIM / BM)       // 16
#define NT_N (N_DIM / BN)       // 43
#define NWG  (NT_M * NT_N)      // 688 (div by 8 -> XCD swizzle bijective)
#define HS 16384                // half-slot bytes (A0 / A1)
#define PS 32768                // parity stride (2 half-slots)

#define WAITV(n) asm volatile("s_waitcnt vmcnt(" #n ")" ::: "memory")
#define BARR     do { asm volatile("" ::: "memory"); __builtin_amdgcn_s_barrier(); asm volatile("" ::: "memory"); } while (0)
#define SCHED0   __builtin_amdgcn_sched_barrier(0)

__global__ __launch_bounds__(512, 2) void gemm_i8(const signed char* __restrict__ Xq,
                                                  const signed char* __restrict__ Wq,
                                                  const float* __restrict__ sc,
                                                  const float* __restrict__ zp,
                                                  const float* __restrict__ rbuf,
                                                  const float* __restrict__ sxbuf,
                                                  float* __restrict__ C) {
  __shared__ __align__(16) unsigned char lds8[65536];  // 64 KiB: 2 parities x {A0,A1}

  const int t = threadIdx.x;
  const int bid = blockIdx.x;
  const int swz = (bid & 7) * (NWG / 8) + (bid >> 3);  // T1 XCD swizzle
  const int tm = swz & 15;   // M-tile
  const int tn = swz >> 4;   // N-tile (consecutive swz share the W-panel -> B L2-hot)

  // --- A staging: thread t owns chunks c0=t (rows 0..63) and c1=t+512 (rows 64..127)
  // of each half. chunk c: row=c>>3, slot j=c&7, global chunk g = j ^ (row&7).
  const int srow = t >> 3;
  const int g0 = (t & 7) ^ (srow & 7);
  const int koff = g0 * 16;
  const signed char* pA0c0 = Xq + (size_t)(tm * BM + srow) * K_DIM + koff;
  const signed char* pA0c1 = Xq + (size_t)(tm * BM + 64 + srow) * K_DIM + koff;
  const signed char* pA1c0 = Xq + (size_t)(tm * BM + 128 + srow) * K_DIM + koff;
  const signed char* pA1c1 = Xq + (size_t)(tm * BM + 192 + srow) * K_DIM + koff;
  const int d0 = t * 16;           // linear LDS byte offset within a half-slot (m104 rule)
  const int d1 = d0 + 8192;

  // --- wave / lane geometry (8 waves = 2M x 4N, wave-tile 128x64; frozen since R7)
  const int lane = t & 63;
  const int w = t >> 6;
  const int wm = w >> 2;          // A-half (0/1)
  const int wn = w & 3;           // B col group
  const int lr = lane & 15, lk = lane >> 4;

  // A fragment read base (bytes): + P*PS + m*2048; kk=1 -> ^64.
  const int j0 = lk ^ (lr & 7);
  const int aP0 = wm * HS + lr * 128 + j0 * 16;

  // B direct-load lane base: row = tn*256 + (wn>>1)*128 + (wn&1)*64 + lr; +n*16 rows/frag.
  const signed char* pBl = Wq + (size_t)(tn * BN + (wn >> 1) * 128 + (wn & 1) * 64 + lr) * K_DIM + lk * 16;

  i32x4 acc[8][4] = {};
  i32x4 bA[4], bB[4], bc1[4];

#define GLL(src, dstoff) \
  __builtin_amdgcn_global_load_lds((const AS1 void*)(src), (AS3 void*)(lds8 + (dstoff)), 16, 0, 0)

  // ---- prologue: B kk0(tile0) -> bA; stage A(tile0) -> parity0
#pragma unroll
  for (int n = 0; n < 4; ++n)
    bA[n] = *(const i32x4*)(pBl + (size_t)n * 16 * K_DIM);
  GLL(pA0c0, d0); GLL(pA0c1, d1);
  GLL(pA1c0, HS + d0); GLL(pA1c1, HS + d1);
  pA0c0 += BK; pA0c1 += BK; pA1c0 += BK; pA1c1 += BK;   // next stage: tile 1
  WAITV(0);
  BARR;

  // TILE: BC = current-tile kk0 B regs, BN_ = next-tile kk0 B regs.
  // SA: stage A(t+1) -> parity P^1.  SB: load kk0(t+1) -> BN_.  WEND: end fence.
#define TILE(P, BC, BN_, SA, SB, WEND) do {                                                \
    i32x4 a[4];                                                                            \
    /* ---- P1: issue B loads (kk1 cur, kk0 next) + A-GLLs; read a m0-3 kk0; MFMA ---- */  \
    _Pragma("unroll") for (int n = 0; n < 4; ++n)                                          \
      bc1[n] = *(const i32x4*)(pBl + 64 + (size_t)n * 16 * K_DIM);                         \
    if (SB) { _Pragma("unroll") for (int n = 0; n < 4; ++n)                                \
      BN_[n] = *(const i32x4*)(pBl + BK + (size_t)n * 16 * K_DIM); }                       \
    if (SA) { GLL(pA0c0, ((P) ^ 1) * PS + d0); GLL(pA0c1, ((P) ^ 1) * PS + d1);            \
              GLL(pA1c0, ((P) ^ 1) * PS + HS + d0); GLL(pA1c1, ((P) ^ 1) * PS + HS + d1);  \
              pA0c0 += BK; pA0c1 += BK; pA1c0 += BK; pA1c1 += BK; }                        \
    _Pragma("unroll") for (int i = 0; i < 4; ++i)                                          \
      a[i] = *(const i32x4*)(lds8 + (P) * PS + aP0 + i * 2048);                            \
    SCHED0;                                                                                \
    _Pragma("unroll") for (int i = 0; i < 4; ++i)                                          \
      _Pragma("unroll") for (int n = 0; n < 4; ++n)                                        \
        acc[i][n] = __builtin_amdgcn_mfma_i32_16x16x64_i8(a[i], BC[n], acc[i][n], 0, 0, 0); \
    /* ---- P2: read a m4-7 kk0; MFMA ---- */                                              \
    _Pragma("unroll") for (int i = 0; i < 4; ++i)                                          \
      a[i] = *(const i32x4*)(lds8 + (P) * PS + aP0 + (4 + i) * 2048);                      \
    SCHED0;                                                                                \
    _Pragma("unroll") for (int i = 0; i < 4; ++i)                                          \
      _Pragma("unroll") for (int n = 0; n < 4; ++n)                                        \
        acc[4 + i][n] = __builtin_amdgcn_mfma_i32_16x16x64_i8(a[i], BC[n], acc[4 + i][n], 0, 0, 0); \
    /* ---- P3: read a m0-3 kk1; MFMA x bc1 (loaded ~1300cyc ago) ---- */                  \
    _Pragma("unroll") for (int i = 0; i < 4; ++i)                                          \
      a[i] = *(const i32x4*)(lds8 + (P) * PS + (aP0 ^ 64) + i * 2048);                     \
    SCHED0;                                                                                \
    _Pragma("unroll") for (int i = 0; i < 4; ++i)                                          \
      _Pragma("unroll") for (int n = 0; n < 4; ++n)                                        \
        acc[i][n] = __builtin_amdgcn_mfma_i32_16x16x64_i8(a[i], bc1[n], acc[i][n], 0, 0, 0); \
    /* ---- P4: read a m4-7 kk1; MFMA x bc1; end fence ---- */                             \
    _Pragma("unroll") for (int i = 0; i < 4; ++i)                                          \
      a[i] = *(const i32x4*)(lds8 + (P) * PS + (aP0 ^ 64) + (4 + i) * 2048);               \
    SCHED0;                                                                                \
    _Pragma("unroll") for (int i = 0; i < 4; ++i)                                          \
      _Pragma("unroll") for (int n = 0; n < 4; ++n)                                        \
        acc[4 + i][n] = __builtin_amdgcn_mfma_i32_16x16x64_i8(a[i], bc1[n], acc[4 + i][n], 0, 0, 0); \
    pBl += BK;                                                                             \
    if (WEND) { WAITV(0); BARR; }                                                          \
  } while (0)

  // main loop: tiles 0..29 (15 x 2), then 30 (stages/loads for 31), then 31 (no stage)
  for (int it = 0; it < 15; ++it) {
    TILE(0, bA, bB, 1, 1, 1);
    TILE(1, bB, bA, 1, 1, 1);
  }
  TILE(0, bA, bB, 1, 1, 1);   // t=30
  TILE(1, bB, bA, 0, 0, 0);   // t=31: no stage, no fence

#undef TILE
#undef GLL

  // epilogue: C/D layout col=lane&15, row=(lane>>4)*4+reg (dtype-independent, validated)
  const int row0 = tm * BM + wm * 128 + lk * 4;
  const int col0 = tn * BN + wn * 64 + lr;
  float sv[4], zv[4];
#pragma unroll
  for (int n = 0; n < 4; ++n) {
    sv[n] = sc[col0 + n * 16];
    zv[n] = 7.5f - zp[col0 + n * 16];
  }
#pragma unroll
  for (int m = 0; m < 8; ++m)
#pragma unroll
    for (int rr = 0; rr < 4; ++rr) {
      const int row = row0 + m * 16 + rr;
      const float rv = rbuf[row];
      const float hx = 0.5f * sxbuf[row];
#pragma unroll
      for (int n = 0; n < 4; ++n)
        C[(size_t)row * N_DIM + col0 + n * 16] = sv[n] * (hx * (float)acc[m][n][rr] + zv[n] * rv);
    }
}

// ---------------- Fallback: fp32 LDS-tiled GEMM reading packed weights (ws too small) ----------------
__global__ __launch_bounds__(256) void fallback_gemm(const float* __restrict__ x,
                                                     const int* __restrict__ pw,
                                                     const float* __restrict__ sc,
                                                     const float* __restrict__ zp,
                                                     float* __restrict__ out) {
  __shared__ float Xs[64][33];
  __shared__ float Ws[64][33];
  const int bid = blockIdx.x;
  const int bm = bid & 63;
  const int bn = bid >> 6;
  const int t = threadIdx.x;
  const int tx = t & 15, ty = t >> 4;
  float acc[4][4] = {};
  for (int k0 = 0; k0 < K_DIM; k0 += 32) {
    __syncthreads();
#pragma unroll
    for (int i = 0; i < 8; ++i) {
      int e = t + i * 256; int rr = e >> 5, c = e & 31;
      Xs[rr][c] = x[(size_t)(bm * 64 + rr) * K_DIM + k0 + c];
    }
#pragma unroll
    for (int i = 0; i < 4; ++i) {
      int e = t + i * 256; int rr = e >> 4, jj = e & 15;
      int row = bn * 64 + rr;
      int v = pw[(size_t)row * KP + (k0 >> 1) + jj];
      float s = sc[row], z = zp[row];
      Ws[rr][2 * jj]     = ((float)(v & 15) - z) * s;
      Ws[rr][2 * jj + 1] = ((float)((v >> 4) & 15) - z) * s;
    }
    __syncthreads();
#pragma unroll
    for (int kk = 0; kk < 32; ++kk) {
      float a[4], b[4];
#pragma unroll
      for (int i2 = 0; i2 < 4; ++i2) a[i2] = Xs[ty * 4 + i2][kk];
#pragma unroll
      for (int j2 = 0; j2 < 4; ++j2) b[j2] = Ws[tx * 4 + j2][kk];
#pragma unroll
      for (int i2 = 0; i2 < 4; ++i2)
#pragma unroll
        for (int j2 = 0; j2 < 4; ++j2) acc[i2][j2] += a[i2] * b[j2];
    }
  }
#pragma unroll
  for (int i2 = 0; i2 < 4; ++i2)
#pragma unroll
    for (int j2 = 0; j2 < 4; ++j2)
      out[(size_t)(bm * 64 + ty * 4 + i2) * N_DIM + bn * 64 + tx * 4 + j2] = acc[i2][j2];
}

extern "C" void kernel_launch(void* const* d_in, const int* in_sizes, int n_in,
                              void* d_out, int out_size, void* d_ws, size_t ws_size,
                              hipStream_t stream) {
  const float* x  = (const float*)d_in[0];
  const int*   pw = (const int*)d_in[1];
  const float* sc = (const float*)d_in[2];
  const float* zp = (const float*)d_in[3];
  float* out = (float*)d_out;

  const size_t wq_b = (size_t)N_DIM * K_DIM;   // 45,088,768
  const size_t xq_b = (size_t)M_DIM * K_DIM;   // 16,777,216
  const size_t need = wq_b + xq_b + 2 * 4096 * sizeof(float);

  if (ws_size >= need) {
    signed char* wq = (signed char*)d_ws;
    signed char* xq = wq + wq_b;
    float* rbuf  = (float*)((char*)d_ws + wq_b + xq_b);
    float* sxbuf = rbuf + 4096;
    hipLaunchKernelGGL(prep,    dim3(4096 + 2048), dim3(256), 0, stream, x, pw, xq, wq, rbuf, sxbuf);
    hipLaunchKernelGGL(gemm_i8, dim3(NWG),         dim3(512), 0, stream, xq, wq, sc, zp, rbuf, sxbuf, out);
  } else {
    hipLaunchKernelGGL(fallback_gemm, dim3(64 * 172), dim3(256), 0, stream, x, pw, sc, zp, out);
  }
}

// Round 14
// 215.172 us; speedup vs baseline: 1.5088x; 1.5088x over previous
//
#include <hip/hip_runtime.h>
#include <hip/hip_bf16.h>
#include <stdint.h>

#define M_DIM 4096
#define N_DIM 11008
#define K_DIM 4096
#define KP    (K_DIM / 2)   // packed int32s per weight row

typedef __attribute__((ext_vector_type(4))) int i32x4;

#define AS1 __attribute__((address_space(1)))
#define AS3 __attribute__((address_space(3)))

// ---------------- Fused pre-pass: quant_x (blocks 0..4095) + pack_q (blocks 4096..8191) ----------------
// R14: w-pack gets 4096 blocks (was 2048) -- balances per-block bytes (~33 KB vs x-quant ~20 KB)
// so prep makespan is not set by 3x-longer w-pack blocks.
__global__ __launch_bounds__(256) void prep(const float* __restrict__ x,
                                            const int* __restrict__ pw,
                                            signed char* __restrict__ xq,
                                            signed char* __restrict__ wq,
                                            float* __restrict__ r,
                                            float* __restrict__ sx) {
  const int b = blockIdx.x;
  const int t = threadIdx.x;
  if (b < 4096) {
    // --- per-row quantize x -> i8, emit r[b]=sum(x), sx[b]=scale ---
    const int row = b;
    const int lane = t & 63, wid = t >> 6;
    const float4* x4 = (const float4*)(x + (size_t)row * K_DIM);
    float4 v[4];
    float am = 0.0f, sm = 0.0f;
#pragma unroll
    for (int i = 0; i < 4; ++i) {
      v[i] = x4[i * 256 + t];
      sm += v[i].x + v[i].y + v[i].z + v[i].w;
      am = fmaxf(am, fmaxf(fmaxf(fabsf(v[i].x), fabsf(v[i].y)),
                           fmaxf(fabsf(v[i].z), fabsf(v[i].w))));
    }
#pragma unroll
    for (int off = 32; off >= 1; off >>= 1) {
      am = fmaxf(am, __shfl_xor(am, off));
      sm += __shfl_xor(sm, off);
    }
    __shared__ float smax[4], ssum[4];
    if (lane == 0) { smax[wid] = am; ssum[wid] = sm; }
    __syncthreads();
    am = fmaxf(fmaxf(smax[0], smax[1]), fmaxf(smax[2], smax[3]));
    sm = ssum[0] + ssum[1] + ssum[2] + ssum[3];
    const float inv = am > 0.0f ? 127.0f / am : 0.0f;
    unsigned int* xo = (unsigned int*)(xq + (size_t)row * K_DIM);
#pragma unroll
    for (int i = 0; i < 4; ++i) {
      int q0 = min(127, max(-127, __float2int_rn(v[i].x * inv)));
      int q1 = min(127, max(-127, __float2int_rn(v[i].y * inv)));
      int q2 = min(127, max(-127, __float2int_rn(v[i].z * inv)));
      int q3 = min(127, max(-127, __float2int_rn(v[i].w * inv)));
      xo[i * 256 + t] = ((unsigned int)q0 & 0xFF) | (((unsigned int)q1 & 0xFF) << 8) |
                        (((unsigned int)q2 & 0xFF) << 16) | (((unsigned int)q3 & 0xFF) << 24);
    }
    if (t == 0) { r[row] = sm; sx[row] = am > 0.0f ? am / 127.0f : 0.0f; }
  } else {
    // --- repack nibbles -> q' = 2q-15 as i8 [N][K] ---
    const int total = (N_DIM * KP) / 4;  // int4 items; 4 int32 -> 8 i8
    for (int i = (b - 4096) * 256 + t; i < total; i += 4096 * 256) {
      int4 p = ((const int4*)pw)[i];
      int v[4] = {p.x, p.y, p.z, p.w};
      unsigned int u0 = 0, u1 = 0;
#pragma unroll
      for (int j = 0; j < 2; ++j) {
        unsigned int b0 = (unsigned int)(2 * (v[j] & 15) - 15) & 0xFF;
        unsigned int b1 = (unsigned int)(2 * ((v[j] >> 4) & 15) - 15) & 0xFF;
        u0 |= (b0 | (b1 << 8)) << (16 * j);
      }
#pragma unroll
      for (int j = 0; j < 2; ++j) {
        unsigned int b0 = (unsigned int)(2 * (v[2 + j] & 15) - 15) & 0xFF;
        unsigned int b1 = (unsigned int)(2 * ((v[2 + j] >> 4) & 15) - 15) & 0xFF;
        u1 |= (b0 | (b1 << 8)) << (16 * j);
      }
      uint2 st; st.x = u0; st.y = u1;
      ((uint2*)wq)[i] = st;
    }
  }
}

// ---------------- Main: 256x256 tile, BK=128 (i8), pipelined i8 MFMA GEMM (R11, proven best) ----------------
// G'[M,N] = Xq[M,K] @ Wq[N,K]^T in i32; epilogue: out = s[o]*(0.5*sx[b]*G' + (7.5-zp[o])*r[b]).
// Frozen structure (R11): barrier-diet fences (mid WAITL0+BARR protecting B-slot WAR, end
// WAITV(4)+BARR counted-vmcnt), phase-pipelined ds_reads with sched_barrier pinning, NO
// setprio (R11: +7%; starved sibling wave's LDS issue), 128B-row XOR-swizzled LDS
// (0 conflicts R7-R13), linear GLL dst (m104). Doors closed by experiment: R5 full hoist
// (reg cliff), R8 64B-row small tile (conflicts+traffic), R12 16-wave (barrier-locked
// occupancy useless), R13 B-direct (vmcnt FIFO poison). Ring algebra: mid fence is
// structurally minimal for 2-parity A + <=4-slot B in 128 KB LDS.
#define BM 256
#define BN 256
#define BK 128                  // i8 elements per K-tile
#define NTILE (K_DIM / BK)      // 32
#define NT_M (M_DIM / BM)       // 16
#define NT_N (N_DIM / BN)       // 43
#define NWG  (NT_M * NT_N)      // 688 (div by 8 -> XCD swizzle bijective)
#define HS 16384                // half-slot bytes
#define PS 65536                // parity stride (4 half-slots)

#define WAITV(n) asm volatile("s_waitcnt vmcnt(" #n ")" ::: "memory")
#define WAITL0   asm volatile("s_waitcnt lgkmcnt(0)" ::: "memory")
#define BARR     do { asm volatile("" ::: "memory"); __builtin_amdgcn_s_barrier(); asm volatile("" ::: "memory"); } while (0)
#define SCHED0   __builtin_amdgcn_sched_barrier(0)

__global__ __launch_bounds__(512, 2) void gemm_i8(const signed char* __restrict__ Xq,
                                                  const signed char* __restrict__ Wq,
                                                  const float* __restrict__ sc,
                                                  const float* __restrict__ zp,
                                                  const float* __restrict__ rbuf,
                                                  const float* __restrict__ sxbuf,
                                                  float* __restrict__ C) {
  __shared__ __align__(16) unsigned char lds8[131072];  // 128 KiB

  const int t = threadIdx.x;
  const int bid = blockIdx.x;
  const int swz = (bid & 7) * (NWG / 8) + (bid >> 3);  // T1 XCD swizzle
  const int tm = swz & 15;   // M-tile
  const int tn = swz >> 4;   // N-tile

  // --- stage sources: thread t owns LDS chunks c0=t (rows 0..63) and c1=t+512 (rows 64..127).
  // chunk c: row = c>>3, slot j = c&7, global chunk g = j ^ (row&7); 16 B per chunk.
  const int srow = t >> 3;
  const int g0 = (t & 7) ^ (srow & 7);
  const int koff = g0 * 16;                      // BYTE offset within K-tile
  const signed char* pB0c0 = Wq + (size_t)(tn * BN + srow) * K_DIM + koff;
  const signed char* pB0c1 = Wq + (size_t)(tn * BN + 64 + srow) * K_DIM + koff;
  const signed char* pB1c0 = Wq + (size_t)(tn * BN + 128 + srow) * K_DIM + koff;
  const signed char* pB1c1 = Wq + (size_t)(tn * BN + 192 + srow) * K_DIM + koff;
  const signed char* pA0c0 = Xq + (size_t)(tm * BM + srow) * K_DIM + koff;
  const signed char* pA0c1 = Xq + (size_t)(tm * BM + 64 + srow) * K_DIM + koff;
  const signed char* pA1c0 = Xq + (size_t)(tm * BM + 128 + srow) * K_DIM + koff;
  const signed char* pA1c1 = Xq + (size_t)(tm * BM + 192 + srow) * K_DIM + koff;
  const int d0 = t * 16;           // linear LDS byte offset of chunk c0 (m104 rule)
  const int d1 = d0 + 8192;        // chunk c1

  // --- wave / lane geometry
  const int lane = t & 63;
  const int w = t >> 6;
  const int wm = w >> 2;          // A-half
  const int wn = w & 3;           // B col group; B-half = wn>>1
  const int lr = lane & 15, lk = lane >> 4;

  // fragment read bases (BYTES). row stride 128 B; frag (row=16m+lr, chunk g=ks*4+lk)
  // at slot j = g ^ (lr&7); ks=1 flips chunk bit2 -> addr ^ 64.
  const int j0 = lk ^ (lr & 7);
  const int aB0 = (2 + wm) * HS + lr * 128 + j0 * 16;
  const int aB1 = aB0 ^ 64;
  const int bB0 = (wn >> 1) * HS + (wn & 1) * 8192 + lr * 128 + j0 * 16;
  const int bB1 = bB0 ^ 64;

  i32x4 acc[8][4] = {};

#define GLL(src, dstoff) \
  __builtin_amdgcn_global_load_lds((const AS1 void*)(src), (AS3 void*)(lds8 + (dstoff)), 16, 0, 0)

  // ---- prologue: stage B0,B1,A0,A1 of tile0 (parity0), B0,B1 of tile1 (parity1)
  GLL(pB0c0, 0 * HS + d0); GLL(pB0c1, 0 * HS + d1);
  GLL(pB1c0, 1 * HS + d0); GLL(pB1c1, 1 * HS + d1);
  GLL(pA0c0, 2 * HS + d0); GLL(pA0c1, 2 * HS + d1);
  GLL(pA1c0, 3 * HS + d0); GLL(pA1c1, 3 * HS + d1);
  GLL(pB0c0 + BK, 4 * HS + d0); GLL(pB0c1 + BK, 4 * HS + d1);
  GLL(pB1c0 + BK, 5 * HS + d0); GLL(pB1c1 + BK, 5 * HS + d1);
  pB0c0 += 2 * BK; pB0c1 += 2 * BK; pB1c0 += 2 * BK; pB1c1 += 2 * BK;
  pA0c0 += BK;     pA0c1 += BK;     pA1c0 += BK;     pA1c1 += BK;
  WAITV(4);  // tile0 resident; B(tile1) in flight
  BARR;

  // VMODE: 0 -> vmcnt(4), 1 -> vmcnt(0), 2 -> none
#define TILE(P, SA, SB, VMODE) do {                                                        \
    i32x4 a0[4], a1[4], a2[4], a3[4], b0[4], b1[4];                                        \
    /* ---- P1: issue reads a0,b0 AND a1; stage A0(t+1); MFMA a0 x b0 ---- */              \
    _Pragma("unroll") for (int i = 0; i < 4; ++i)                                          \
      a0[i] = *(const i32x4*)(lds8 + (P) * PS + aB0 + i * 2048);                           \
    _Pragma("unroll") for (int n = 0; n < 4; ++n)                                          \
      b0[n] = *(const i32x4*)(lds8 + (P) * PS + bB0 + n * 2048);                           \
    _Pragma("unroll") for (int i = 0; i < 4; ++i)                                          \
      a1[i] = *(const i32x4*)(lds8 + (P) * PS + aB0 + (4 + i) * 2048);                     \
    if (SA) { GLL(pA0c0, (((P) ^ 1) * 4 + 2) * HS + d0);                                   \
              GLL(pA0c1, (((P) ^ 1) * 4 + 2) * HS + d1);                                   \
              pA0c0 += BK; pA0c1 += BK; }                                                  \
    SCHED0;                                                                                \
    _Pragma("unroll") for (int i = 0; i < 4; ++i)                                          \
      _Pragma("unroll") for (int n = 0; n < 4; ++n)                                        \
        acc[i][n] = __builtin_amdgcn_mfma_i32_16x16x64_i8(a0[i], b0[n], acc[i][n], 0, 0, 0); \
    /* ---- P2: issue reads b1,a2; stage A1(t+1); MFMA a1 x b0; lgkm0; MID BARRIER ---- */ \
    _Pragma("unroll") for (int n = 0; n < 4; ++n)                                          \
      b1[n] = *(const i32x4*)(lds8 + (P) * PS + bB1 + n * 2048);                           \
    _Pragma("unroll") for (int i = 0; i < 4; ++i)                                          \
      a2[i] = *(const i32x4*)(lds8 + (P) * PS + aB1 + i * 2048);                           \
    if (SA) { GLL(pA1c0, (((P) ^ 1) * 4 + 3) * HS + d0);                                   \
              GLL(pA1c1, (((P) ^ 1) * 4 + 3) * HS + d1);                                   \
              pA1c0 += BK; pA1c1 += BK; }                                                  \
    SCHED0;                                                                                \
    _Pragma("unroll") for (int i = 0; i < 4; ++i)                                          \
      _Pragma("unroll") for (int n = 0; n < 4; ++n)                                        \
        acc[4 + i][n] = __builtin_amdgcn_mfma_i32_16x16x64_i8(a1[i], b0[n], acc[4 + i][n], 0, 0, 0); \
    WAITL0;                                                                                \
    BARR;                                                                                  \
    /* ---- P3: issue reads a3; stage B0(t+2); MFMA a2 x b1 ---- */                        \
    _Pragma("unroll") for (int i = 0; i < 4; ++i)                                          \
      a3[i] = *(const i32x4*)(lds8 + (P) * PS + aB1 + (4 + i) * 2048);                     \
    if (SB) { GLL(pB0c0, ((P) * 4 + 0) * HS + d0);                                         \
              GLL(pB0c1, ((P) * 4 + 0) * HS + d1);                                         \
              pB0c0 += BK; pB0c1 += BK; }                                                  \
    SCHED0;                                                                                \
    _Pragma("unroll") for (int i = 0; i < 4; ++i)                                          \
      _Pragma("unroll") for (int n = 0; n < 4; ++n)                                        \
        acc[i][n] = __builtin_amdgcn_mfma_i32_16x16x64_i8(a2[i], b1[n], acc[i][n], 0, 0, 0); \
    /* ---- P4: stage B1(t+2); MFMA a3 x b1; WAITV; END BARRIER ---- */                    \
    if (SB) { GLL(pB1c0, ((P) * 4 + 1) * HS + d0);                                         \
              GLL(pB1c1, ((P) * 4 + 1) * HS + d1);                                         \
              pB1c0 += BK; pB1c1 += BK; }                                                  \
    SCHED0;                                                                                \
    _Pragma("unroll") for (int i = 0; i < 4; ++i)                                          \
      _Pragma("unroll") for (int n = 0; n < 4; ++n)                                        \
        acc[4 + i][n] = __builtin_amdgcn_mfma_i32_16x16x64_i8(a3[i], b1[n], acc[4 + i][n], 0, 0, 0); \
    if ((VMODE) == 0) { WAITV(4); } else if ((VMODE) == 1) { WAITV(0); }                   \
    BARR;                                                                                  \
  } while (0)

  // main loop: tiles 0..29
  for (int it = 0; it < (NTILE - 2) / 2; ++it) {
    TILE(0, 1, 1, 0);
    TILE(1, 1, 1, 0);
  }
  TILE(0, 1, 0, 1);   // tile 30: stage A(31) only; drain
  TILE(1, 0, 0, 2);   // tile 31: no stage, no wait

#undef TILE
#undef GLL

  // epilogue: C/D layout col=lane&15, row=(lane>>4)*4+reg (dtype-independent, validated)
  const int row0 = tm * BM + wm * 128 + lk * 4;
  const int col0 = tn * BN + wn * 64 + lr;
  float sv[4], zv[4];
#pragma unroll
  for (int n = 0; n < 4; ++n) {
    sv[n] = sc[col0 + n * 16];
    zv[n] = 7.5f - zp[col0 + n * 16];
  }
#pragma unroll
  for (int m = 0; m < 8; ++m)
#pragma unroll
    for (int rr = 0; rr < 4; ++rr) {
      const int row = row0 + m * 16 + rr;
      const float rv = rbuf[row];
      const float hx = 0.5f * sxbuf[row];
#pragma unroll
      for (int n = 0; n < 4; ++n)
        C[(size_t)row * N_DIM + col0 + n * 16] = sv[n] * (hx * (float)acc[m][n][rr] + zv[n] * rv);
    }
}

// ---------------- Fallback: fp32 LDS-tiled GEMM reading packed weights (ws too small) ----------------
__global__ __launch_bounds__(256) void fallback_gemm(const float* __restrict__ x,
                                                     const int* __restrict__ pw,
                                                     const float* __restrict__ sc,
                                                     const float* __restrict__ zp,
                                                     float* __restrict__ out) {
  __shared__ float Xs[64][33];
  __shared__ float Ws[64][33];
  const int bid = blockIdx.x;
  const int bm = bid & 63;
  const int bn = bid >> 6;
  const int t = threadIdx.x;
  const int tx = t & 15, ty = t >> 4;
  float acc[4][4] = {};
  for (int k0 = 0; k0 < K_DIM; k0 += 32) {
    __syncthreads();
#pragma unroll
    for (int i = 0; i < 8; ++i) {
      int e = t + i * 256; int rr = e >> 5, c = e & 31;
      Xs[rr][c] = x[(size_t)(bm * 64 + rr) * K_DIM + k0 + c];
    }
#pragma unroll
    for (int i = 0; i < 4; ++i) {
      int e = t + i * 256; int rr = e >> 4, jj = e & 15;
      int row = bn * 64 + rr;
      int v = pw[(size_t)row * KP + (k0 >> 1) + jj];
      float s = sc[row], z = zp[row];
      Ws[rr][2 * jj]     = ((float)(v & 15) - z) * s;
      Ws[rr][2 * jj + 1] = ((float)((v >> 4) & 15) - z) * s;
    }
    __syncthreads();
#pragma unroll
    for (int kk = 0; kk < 32; ++kk) {
      float a[4], b[4];
#pragma unroll
      for (int i2 = 0; i2 < 4; ++i2) a[i2] = Xs[ty * 4 + i2][kk];
#pragma unroll
      for (int j2 = 0; j2 < 4; ++j2) b[j2] = Ws[tx * 4 + j2][kk];
#pragma unroll
      for (int i2 = 0; i2 < 4; ++i2)
#pragma unroll
        for (int j2 = 0; j2 < 4; ++j2) acc[i2][j2] += a[i2] * b[j2];
    }
  }
#pragma unroll
  for (int i2 = 0; i2 < 4; ++i2)
#pragma unroll
    for (int j2 = 0; j2 < 4; ++j2)
      out[(size_t)(bm * 64 + ty * 4 + i2) * N_DIM + bn * 64 + tx * 4 + j2] = acc[i2][j2];
}

extern "C" void kernel_launch(void* const* d_in, const int* in_sizes, int n_in,
                              void* d_out, int out_size, void* d_ws, size_t ws_size,
                              hipStream_t stream) {
  const float* x  = (const float*)d_in[0];
  const int*   pw = (const int*)d_in[1];
  const float* sc = (const float*)d_in[2];
  const float* zp = (const float*)d_in[3];
  float* out = (float*)d_out;

  const size_t wq_b = (size_t)N_DIM * K_DIM;   // 45,088,768
  const size_t xq_b = (size_t)M_DIM * K_DIM;   // 16,777,216
  const size_t need = wq_b + xq_b + 2 * 4096 * sizeof(float);

  if (ws_size >= need) {
    signed char* wq = (signed char*)d_ws;
    signed char* xq = wq + wq_b;
    float* rbuf  = (float*)((char*)d_ws + wq_b + xq_b);
    float* sxbuf = rbuf + 4096;
    hipLaunchKernelGGL(prep,    dim3(4096 + 4096), dim3(256), 0, stream, x, pw, xq, wq, rbuf, sxbuf);
    hipLaunchKernelGGL(gemm_i8, dim3(NWG),         dim3(512), 0, stream, xq, wq, sc, zp, rbuf, sxbuf, out);
  } else {
    hipLaunchKernelGGL(fallback_gemm, dim3(64 * 172), dim3(256), 0, stream, x, pw, sc, zp, out);
  }
}